// Round 13
// baseline (82.848 us; speedup 1.0000x reference)
//
#include <hip/hip_runtime.h>

#define NQ   65536
#define NC   4096
#define SOUT 64
#define NR   4                 // monomials (DEGREE=1, NDIM=3)
#define KTOT (NC + 64)         // 4160: k padded (chunk 64 = poly frags)
#define BM   32                // 32 q-rows per block; 4 waves k-split 4-ways
#define NCH  (NC / 64)         // 64 r2 chunks of BK=64

typedef float    f32x4 __attribute__((ext_vector_type(4)));
typedef _Float16 f16x8 __attribute__((ext_vector_type(8)));
typedef __fp16   h16x2 __attribute__((ext_vector_type(2)));
typedef unsigned uint4v __attribute__((ext_vector_type(4)));

// ---------------- pre-kernels (write d_ws; deterministic every call) ---------

// Fragment-contiguous packed B: bpack[((ch*4+nf)*2+kk)*512 + l*8]; lane l holds
// 8 f16 {coeffs[k][n]}, n=nf*16+(l&15), k=ch*64+kk*32+(l>>4)*8..+7.
// TPS constant 0.5*ln2 folded into kernel coeffs; poly unscaled; zeros after.
__global__ void prep_bpack(const float* __restrict__ coeffs, _Float16* __restrict__ bp) {
    const int idx = blockIdx.x * 256 + threadIdx.x;
    if (idx >= 65 * 4 * 2 * 64) return;
    const int l  = idx & 63;
    const int kk = (idx >> 6) & 1;
    const int nf = (idx >> 7) & 3;
    const int ch = idx >> 9;
    const int n  = nf * 16 + (l & 15);
    const int ks = ch * 64 + kk * 32 + (l >> 4) * 8;
    f16x8 v;
    #pragma unroll
    for (int j = 0; j < 8; ++j) {
        const int k = ks + j;
        float f = 0.0f;
        if (k < NC)           f = coeffs[(size_t)k * SOUT + n] * 0.34657359f;
        else if (k < NC + NR) f = coeffs[(size_t)k * SOUT + n];
        v[j] = (_Float16)f;
    }
    *(f16x8*)(bp + (size_t)idx * 8) = v;
}

// Ye[k] = [-2y0, -2y1, -2y2, 1, |y|^2, 0,0,0] for k < NC, zeros for the pad.
__global__ void prep_ye(const float* __restrict__ y, _Float16* __restrict__ ye) {
    const int k = blockIdx.x * 256 + threadIdx.x;
    if (k >= KTOT) return;
    f16x8 r = {};
    if (k < NC) {
        const float a = y[k * 3 + 0], b = y[k * 3 + 1], c = y[k * 3 + 2];
        r[0] = (_Float16)(-2.0f * a); r[1] = (_Float16)(-2.0f * b);
        r[2] = (_Float16)(-2.0f * c); r[3] = (_Float16)1.0f;
        r[4] = (_Float16)(a * a + b * b + c * c);
    }
    *(f16x8*)(ye + (size_t)k * 8) = r;
}

// ---------------- main kernel ------------------------------------------------
// 4-way K-split: block = 4 waves, all sharing the same 32 q-rows; wave kh
// handles k-chunks [kh*16, kh*16+16). Grid 2048, LDS 24 KB -> 6 blocks/CU ->
// 24 waves/CU TLP with unchanged chip-wide load/VALU/MFMA totals.
// Partials: waves 1..3 write [elem][lane] LDS (conflict-free), wave 0 merges.
// Register A-frag trick: kappa(kt,rho)=(kt&1)*32+(rho>>2)*8+(kt>>1)*4+(rho&3).
__launch_bounds__(256, 6)
__global__ void rbf_mfma11(const float* __restrict__ x,
                           const _Float16* __restrict__ ye,
                           const float* __restrict__ shift,
                           const float* __restrict__ scale,
                           const _Float16* __restrict__ bp,
                           float* __restrict__ out) {
    __shared__ float red[3][32 * 64];   // 24 KB: [src wave-1][elem][lane]

    const int t    = threadIdx.x;
    const int kh   = t >> 6;            // wave = k-quarter
    const int lane = t & 63;
    const int l15  = lane & 15;
    const int lg   = lane >> 4;
    const int qb   = blockIdx.x * BM;   // all waves share these 32 q-rows
    const int s    = kh * 16;           // first chunk of this k-quarter

    // Xe B-fragments per q-half: lg==0 lanes hold [x0,x1,x2,xsq,1,0,0,0]
    f16x8 xef[2];
    uint2  poly01[2];
    #pragma unroll
    for (int qh = 0; qh < 2; ++qh) {
        const int q = qb + qh * 16 + l15;
        const float a = x[q * 3 + 0], b = x[q * 3 + 1], c = x[q * 3 + 2];
        f16x8 v = {};
        if (lg == 0) {
            v[0] = (_Float16)a; v[1] = (_Float16)b; v[2] = (_Float16)c;
            v[3] = (_Float16)(a * a + b * b + c * c); v[4] = (_Float16)1.0f;
        }
        xef[qh] = v;
        h16x2 p0 = __builtin_amdgcn_cvt_pkrtz(1.0f, (a - shift[0]) / scale[0]);
        h16x2 p1 = __builtin_amdgcn_cvt_pkrtz((b - shift[1]) / scale[1],
                                              (c - shift[2]) / scale[2]);
        poly01[qh].x = __builtin_bit_cast(unsigned, p0);
        poly01[qh].y = __builtin_bit_cast(unsigned, p1);
    }

    // per-lane bases
    const _Float16* yeb = ye + ((size_t)((l15 >> 2) * 8 + (l15 & 3))) * 8;  // perm rows
    const _Float16* bpl = bp + (size_t)lane * 8;                            // packed frags

    f32x4 acc[2][4] = {};   // [qh][nf]

    for (int ch = s; ch < s + 16; ++ch) {
        // ---- Y rows (head of the r2 chain; issue first) ----
        f16x8 Y[4];
        #pragma unroll
        for (int kt = 0; kt < 4; ++kt)
            Y[kt] = *(const f16x8*)(yeb + ch * 512 + (kt & 1) * 256 + (kt >> 1) * 32);

        // ---- B fragments: coalesced 1 KB bursts ----
        f16x8 B[4][2];
        #pragma unroll
        for (int nf = 0; nf < 4; ++nf)
            #pragma unroll
            for (int kk = 0; kk < 2; ++kk)
                B[nf][kk] = *(const f16x8*)(bpl + ((size_t)((ch * 4 + nf) * 2 + kk) << 9));

        // ---- per q-half: r2 tiles + f-eval + out-GEMM ----
        #pragma unroll
        for (int qh = 0; qh < 2; ++qh) {
            uint2 w[4];
            #pragma unroll
            for (int kt = 0; kt < 4; ++kt) {
                f32x4 z = {};
                const f32x4 r2 = __builtin_amdgcn_mfma_f32_16x16x32_f16(
                    Y[kt], xef[qh], z, 0, 0, 0);
                float f[4];
                #pragma unroll
                for (int r = 0; r < 4; ++r) {
                    const float rc = fmaxf(r2[r], 1e-37f);
                    f[r] = rc * __log2f(rc);
                }
                h16x2 h0 = __builtin_amdgcn_cvt_pkrtz(f[0], f[1]);
                h16x2 h1 = __builtin_amdgcn_cvt_pkrtz(f[2], f[3]);
                w[kt].x = __builtin_bit_cast(unsigned, h0);
                w[kt].y = __builtin_bit_cast(unsigned, h1);
            }
            const uint4v a0 = {w[0].x, w[0].y, w[2].x, w[2].y};
            const uint4v a1 = {w[1].x, w[1].y, w[3].x, w[3].y};
            const f16x8 af0 = __builtin_bit_cast(f16x8, a0);
            const f16x8 af1 = __builtin_bit_cast(f16x8, a1);
            #pragma unroll
            for (int nf = 0; nf < 4; ++nf) {
                acc[qh][nf] = __builtin_amdgcn_mfma_f32_16x16x32_f16(
                    af0, B[nf][0], acc[qh][nf], 0, 0, 0);
                acc[qh][nf] = __builtin_amdgcn_mfma_f32_16x16x32_f16(
                    af1, B[nf][1], acc[qh][nf], 0, 0, 0);
            }
        }
    }

    if (kh == 3) {
        // ---- poly tail: chunk 64, kk=0 frags; A = [1,xh0,xh1,xh2,0...] ----
        #pragma unroll
        for (int qh = 0; qh < 2; ++qh) {
            uint4v ap = {};
            if (lg == 0) { ap.x = poly01[qh].x; ap.y = poly01[qh].y; }
            const f16x8 afp = __builtin_bit_cast(f16x8, ap);
            #pragma unroll
            for (int nf = 0; nf < 4; ++nf) {
                const f16x8 bpf = *(const f16x8*)(
                    bpl + ((size_t)((NCH * 4 + nf) * 2) << 9));
                acc[qh][nf] = __builtin_amdgcn_mfma_f32_16x16x32_f16(
                    afp, bpf, acc[qh][nf], 0, 0, 0);
            }
        }
    }

    if (kh != 0) {
        // write partials: [elem][lane] layout -> conflict-free b32 stores
        #pragma unroll
        for (int qh = 0; qh < 2; ++qh)
            #pragma unroll
            for (int nf = 0; nf < 4; ++nf)
                #pragma unroll
                for (int r = 0; r < 4; ++r)
                    red[kh - 1][(qh * 16 + nf * 4 + r) * 64 + lane] = acc[qh][nf][r];
    }
    __syncthreads();
    if (kh == 0) {
        #pragma unroll
        for (int qh = 0; qh < 2; ++qh)
            #pragma unroll
            for (int nf = 0; nf < 4; ++nf)
                #pragma unroll
                for (int r = 0; r < 4; ++r) {
                    const int e = (qh * 16 + nf * 4 + r) * 64 + lane;
                    acc[qh][nf][r] += (red[0][e] + red[1][e]) + red[2][e];
                }

        // epilogue: C/D col=lane&15 (n), row=lg*4+r (q)
        #pragma unroll
        for (int qh = 0; qh < 2; ++qh)
            #pragma unroll
            for (int nf = 0; nf < 4; ++nf)
                #pragma unroll
                for (int r = 0; r < 4; ++r)
                    out[(size_t)(qb + qh * 16 + lg * 4 + r) * SOUT + nf * 16 + l15] =
                        acc[qh][nf][r];
    }
}

// ---------------- fallback (round-1 kernel) if d_ws too small ----------------
__launch_bounds__(256)
__global__ void rbf_tps_fallback(const float* __restrict__ x,
                                 const float* __restrict__ y,
                                 const float* __restrict__ coeffs,
                                 const float* __restrict__ shift,
                                 const float* __restrict__ scale,
                                 float* __restrict__ out) {
    __shared__ float4 ytile[NC];
    const int tid = threadIdx.x;
    for (int j = tid; j < NC; j += 256) {
        const float a = y[j * 3], b = y[j * 3 + 1], c = y[j * 3 + 2];
        ytile[j] = make_float4(a, b, c, a * a + b * b + c * c);
    }
    __syncthreads();
    const int q = blockIdx.x * 256 + tid;
    const float x0 = x[q * 3], x1 = x[q * 3 + 1], x2 = x[q * 3 + 2];
    const float xsq = x0 * x0 + x1 * x1 + x2 * x2;
    const float xh0 = (x0 - shift[0]) / scale[0];
    const float xh1 = (x1 - shift[1]) / scale[1];
    const float xh2 = (x2 - shift[2]) / scale[2];
    float acc[SOUT];
    {
        const float* c0 = &coeffs[(size_t)(NC + 0) * SOUT];
        const float* c1 = &coeffs[(size_t)(NC + 1) * SOUT];
        const float* c2 = &coeffs[(size_t)(NC + 2) * SOUT];
        const float* c3 = &coeffs[(size_t)(NC + 3) * SOUT];
        #pragma unroll
        for (int s = 0; s < SOUT; ++s)
            acc[s] = c0[s] + xh0 * c1[s] + xh1 * c2[s] + xh2 * c3[s];
    }
    #pragma unroll 2
    for (int j = 0; j < NC; ++j) {
        const float4 yj = ytile[j];
        const float dot = x0 * yj.x + x1 * yj.y + x2 * yj.z;
        float r2 = fmaf(-2.0f, dot, xsq + yj.w);
        r2 = fmaxf(r2, 0.0f);
        const float f = 0.5f * r2 * __logf(fmaxf(r2, 1e-37f));
        const float* __restrict__ cj = &coeffs[(size_t)j * SOUT];
        #pragma unroll
        for (int s = 0; s < SOUT; ++s) acc[s] = fmaf(f, cj[s], acc[s]);
    }
    float4* o4 = (float4*)&out[(size_t)q * SOUT];
    #pragma unroll
    for (int s = 0; s < SOUT / 4; ++s)
        o4[s] = make_float4(acc[4 * s], acc[4 * s + 1], acc[4 * s + 2], acc[4 * s + 3]);
}

extern "C" void kernel_launch(void* const* d_in, const int* in_sizes, int n_in,
                              void* d_out, int out_size, void* d_ws, size_t ws_size,
                              hipStream_t stream) {
    const float* x      = (const float*)d_in[0];
    const float* y      = (const float*)d_in[1];
    const float* coeffs = (const float*)d_in[2];
    const float* shift  = (const float*)d_in[3];
    const float* scale  = (const float*)d_in[4];
    float* out = (float*)d_out;

    const size_t bp_bytes = (size_t)65 * 4 * 2 * 64 * 8 * sizeof(_Float16); // 532,480
    const size_t ye_bytes = (size_t)KTOT * 8 * sizeof(_Float16);            //  66,560

    if (ws_size >= bp_bytes + ye_bytes) {
        _Float16* bpw = (_Float16*)d_ws;
        _Float16* yep = (_Float16*)((char*)d_ws + bp_bytes);
        hipLaunchKernelGGL(prep_bpack, dim3((65 * 4 * 2 * 64 + 255) / 256), dim3(256),
                           0, stream, coeffs, bpw);
        hipLaunchKernelGGL(prep_ye, dim3((KTOT + 255) / 256), dim3(256),
                           0, stream, y, yep);
        hipLaunchKernelGGL(rbf_mfma11, dim3(NQ / BM), dim3(256), 0, stream,
                           x, yep, shift, scale, bpw, out);
    } else {
        hipLaunchKernelGGL(rbf_tps_fallback, dim3(NQ / 256), dim3(256),
                           0, stream, x, y, coeffs, shift, scale, out);
    }
}

// Round 16
// 68.935 us; speedup vs baseline: 1.2018x; 1.2018x over previous
//
#include <hip/hip_runtime.h>

#define NQ   65536
#define NC   4096
#define SOUT 64
#define NR   4                 // monomials (DEGREE=1, NDIM=3)
#define KTOT (NC + 64)         // 4160: k padded (chunk 64 = poly frags)
#define BM   64                // 2 q-groups x 32 q-rows per block
#define NCH  (NC / 64)         // 64 r2 chunks of BK=64

typedef float    f32x4 __attribute__((ext_vector_type(4)));
typedef _Float16 f16x8 __attribute__((ext_vector_type(8)));
typedef __fp16   h16x2 __attribute__((ext_vector_type(2)));
typedef unsigned uint4v __attribute__((ext_vector_type(4)));

// ---------------- pre-kernels (write d_ws; deterministic every call) ---------

// Fragment-contiguous packed B: bpack[((ch*4+nf)*2+kk)*512 + l*8]; lane l holds
// 8 f16 {coeffs[k][n]}, n=nf*16+(l&15), k=ch*64+kk*32+(l>>4)*8..+7.
// TPS constant 0.5*ln2 folded into kernel coeffs; poly unscaled; zeros after.
__global__ void prep_bpack(const float* __restrict__ coeffs, _Float16* __restrict__ bp) {
    const int idx = blockIdx.x * 256 + threadIdx.x;
    if (idx >= 65 * 4 * 2 * 64) return;
    const int l  = idx & 63;
    const int kk = (idx >> 6) & 1;
    const int nf = (idx >> 7) & 3;
    const int ch = idx >> 9;
    const int n  = nf * 16 + (l & 15);
    const int ks = ch * 64 + kk * 32 + (l >> 4) * 8;
    f16x8 v;
    #pragma unroll
    for (int j = 0; j < 8; ++j) {
        const int k = ks + j;
        float f = 0.0f;
        if (k < NC)           f = coeffs[(size_t)k * SOUT + n] * 0.34657359f;
        else if (k < NC + NR) f = coeffs[(size_t)k * SOUT + n];
        v[j] = (_Float16)f;
    }
    *(f16x8*)(bp + (size_t)idx * 8) = v;
}

// Ye[k] = [-2y0, -2y1, -2y2, 1, |y|^2 + 0.02, 0,0,0] for k < NC; zeros padded.
// +0.02 keeps the MFMA-computed r2 strictly positive against f16 input noise
// (|noise| <~ 0.02), removing the per-eval clamp. Output error <= ~0.3 abs.
__global__ void prep_ye(const float* __restrict__ y, _Float16* __restrict__ ye) {
    const int k = blockIdx.x * 256 + threadIdx.x;
    if (k >= KTOT) return;
    f16x8 r = {};
    if (k < NC) {
        const float a = y[k * 3 + 0], b = y[k * 3 + 1], c = y[k * 3 + 2];
        r[0] = (_Float16)(-2.0f * a); r[1] = (_Float16)(-2.0f * b);
        r[2] = (_Float16)(-2.0f * c); r[3] = (_Float16)1.0f;
        r[4] = (_Float16)(a * a + b * b + c * c + 0.02f);
    }
    *(f16x8*)(ye + (size_t)k * 8) = r;
}

// ---------------- main kernel ------------------------------------------------
// Round-12 structure (best passing: 74.7 us kernel): 2-way K-split, plain C++
// loads, register A-frag trick, LDS merge. Change vs round 12: no fmax clamp —
// ysq bias guarantees r2>0; log uses the free |.| input modifier. No inline asm.
__launch_bounds__(256, 4)
__global__ void rbf_mfma14(const float* __restrict__ x,
                           const _Float16* __restrict__ ye,
                           const float* __restrict__ shift,
                           const float* __restrict__ scale,
                           const _Float16* __restrict__ bp,
                           float* __restrict__ out) {
    __shared__ float red[2][32 * 64];   // 16 KB: [qg][elem][lane]

    const int t    = threadIdx.x;
    const int wave = t >> 6;
    const int lane = t & 63;
    const int l15  = lane & 15;
    const int lg   = lane >> 4;
    const int qg   = wave & 1;
    const int kh   = wave >> 1;
    const int qb   = blockIdx.x * BM + qg * 32;   // this wave's 32 q-rows
    const int s    = kh * 32;                     // first chunk of this k-half

    // Xe B-fragments per q-half: lg==0 lanes hold [x0,x1,x2,xsq,1,0,0,0]
    f16x8 xef[2];
    uint2  poly01[2];
    #pragma unroll
    for (int qh = 0; qh < 2; ++qh) {
        const int q = qb + qh * 16 + l15;
        const float a = x[q * 3 + 0], b = x[q * 3 + 1], c = x[q * 3 + 2];
        f16x8 v = {};
        if (lg == 0) {
            v[0] = (_Float16)a; v[1] = (_Float16)b; v[2] = (_Float16)c;
            v[3] = (_Float16)(a * a + b * b + c * c); v[4] = (_Float16)1.0f;
        }
        xef[qh] = v;
        h16x2 p0 = __builtin_amdgcn_cvt_pkrtz(1.0f, (a - shift[0]) / scale[0]);
        h16x2 p1 = __builtin_amdgcn_cvt_pkrtz((b - shift[1]) / scale[1],
                                              (c - shift[2]) / scale[2]);
        poly01[qh].x = __builtin_bit_cast(unsigned, p0);
        poly01[qh].y = __builtin_bit_cast(unsigned, p1);
    }

    // per-lane bases
    const _Float16* yeb = ye + ((size_t)((l15 >> 2) * 8 + (l15 & 3))) * 8;  // perm rows
    const _Float16* bpl = bp + (size_t)lane * 8;                            // packed frags

    f32x4 acc[2][4] = {};   // [qh][nf]

    for (int ch = s; ch < s + 32; ++ch) {
        // ---- Y rows (head of the r2 chain; issue first) ----
        f16x8 Y[4];
        #pragma unroll
        for (int kt = 0; kt < 4; ++kt)
            Y[kt] = *(const f16x8*)(yeb + ch * 512 + (kt & 1) * 256 + (kt >> 1) * 32);

        // ---- B fragments: coalesced 1 KB bursts (same addrs on all waves) ----
        f16x8 B[4][2];
        #pragma unroll
        for (int nf = 0; nf < 4; ++nf)
            #pragma unroll
            for (int kk = 0; kk < 2; ++kk)
                B[nf][kk] = *(const f16x8*)(bpl + ((size_t)((ch * 4 + nf) * 2 + kk) << 9));

        // ---- per q-half: r2 tiles + f-eval + out-GEMM ----
        #pragma unroll
        for (int qh = 0; qh < 2; ++qh) {
            uint2 w[4];
            #pragma unroll
            for (int kt = 0; kt < 4; ++kt) {
                f32x4 z = {};
                const f32x4 r2 = __builtin_amdgcn_mfma_f32_16x16x32_f16(
                    Y[kt], xef[qh], z, 0, 0, 0);
                float f[4];
                #pragma unroll
                for (int r = 0; r < 4; ++r) {
                    // r2 > 0 by ysq bias; |.| folds into v_log as input modifier
                    f[r] = r2[r] * __log2f(__builtin_fabsf(r2[r]));
                }
                h16x2 h0 = __builtin_amdgcn_cvt_pkrtz(f[0], f[1]);
                h16x2 h1 = __builtin_amdgcn_cvt_pkrtz(f[2], f[3]);
                w[kt].x = __builtin_bit_cast(unsigned, h0);
                w[kt].y = __builtin_bit_cast(unsigned, h1);
            }
            const uint4v a0 = {w[0].x, w[0].y, w[2].x, w[2].y};
            const uint4v a1 = {w[1].x, w[1].y, w[3].x, w[3].y};
            const f16x8 af0 = __builtin_bit_cast(f16x8, a0);
            const f16x8 af1 = __builtin_bit_cast(f16x8, a1);
            #pragma unroll
            for (int nf = 0; nf < 4; ++nf) {
                acc[qh][nf] = __builtin_amdgcn_mfma_f32_16x16x32_f16(
                    af0, B[nf][0], acc[qh][nf], 0, 0, 0);
                acc[qh][nf] = __builtin_amdgcn_mfma_f32_16x16x32_f16(
                    af1, B[nf][1], acc[qh][nf], 0, 0, 0);
            }
        }
    }

    if (kh == 1) {
        // ---- poly tail: chunk 64, kk=0 frags; A = [1,xh0,xh1,xh2,0...] ----
        #pragma unroll
        for (int qh = 0; qh < 2; ++qh) {
            uint4v ap = {};
            if (lg == 0) { ap.x = poly01[qh].x; ap.y = poly01[qh].y; }
            const f16x8 afp = __builtin_bit_cast(f16x8, ap);
            #pragma unroll
            for (int nf = 0; nf < 4; ++nf) {
                const f16x8 bpf = *(const f16x8*)(
                    bpl + ((size_t)((NCH * 4 + nf) * 2) << 9));
                acc[qh][nf] = __builtin_amdgcn_mfma_f32_16x16x32_f16(
                    afp, bpf, acc[qh][nf], 0, 0, 0);
            }
        }
        // write partials: [elem][lane] layout -> conflict-free b32 stores
        #pragma unroll
        for (int qh = 0; qh < 2; ++qh)
            #pragma unroll
            for (int nf = 0; nf < 4; ++nf)
                #pragma unroll
                for (int r = 0; r < 4; ++r)
                    red[qg][(qh * 16 + nf * 4 + r) * 64 + lane] = acc[qh][nf][r];
    }
    __syncthreads();
    if (kh == 0) {
        #pragma unroll
        for (int qh = 0; qh < 2; ++qh)
            #pragma unroll
            for (int nf = 0; nf < 4; ++nf)
                #pragma unroll
                for (int r = 0; r < 4; ++r)
                    acc[qh][nf][r] += red[qg][(qh * 16 + nf * 4 + r) * 64 + lane];

        // epilogue: C/D col=lane&15 (n), row=lg*4+r (q)
        #pragma unroll
        for (int qh = 0; qh < 2; ++qh)
            #pragma unroll
            for (int nf = 0; nf < 4; ++nf)
                #pragma unroll
                for (int r = 0; r < 4; ++r)
                    out[(size_t)(qb + qh * 16 + lg * 4 + r) * SOUT + nf * 16 + l15] =
                        acc[qh][nf][r];
    }
}

// ---------------- fallback (round-1 kernel) if d_ws too small ----------------
__launch_bounds__(256)
__global__ void rbf_tps_fallback(const float* __restrict__ x,
                                 const float* __restrict__ y,
                                 const float* __restrict__ coeffs,
                                 const float* __restrict__ shift,
                                 const float* __restrict__ scale,
                                 float* __restrict__ out) {
    __shared__ float4 ytile[NC];
    const int tid = threadIdx.x;
    for (int j = tid; j < NC; j += 256) {
        const float a = y[j * 3], b = y[j * 3 + 1], c = y[j * 3 + 2];
        ytile[j] = make_float4(a, b, c, a * a + b * b + c * c);
    }
    __syncthreads();
    const int q = blockIdx.x * 256 + tid;
    const float x0 = x[q * 3], x1 = x[q * 3 + 1], x2 = x[q * 3 + 2];
    const float xsq = x0 * x0 + x1 * x1 + x2 * x2;
    const float xh0 = (x0 - shift[0]) / scale[0];
    const float xh1 = (x1 - shift[1]) / scale[1];
    const float xh2 = (x2 - shift[2]) / scale[2];
    float acc[SOUT];
    {
        const float* c0 = &coeffs[(size_t)(NC + 0) * SOUT];
        const float* c1 = &coeffs[(size_t)(NC + 1) * SOUT];
        const float* c2 = &coeffs[(size_t)(NC + 2) * SOUT];
        const float* c3 = &coeffs[(size_t)(NC + 3) * SOUT];
        #pragma unroll
        for (int s = 0; s < SOUT; ++s)
            acc[s] = c0[s] + xh0 * c1[s] + xh1 * c2[s] + xh2 * c3[s];
    }
    #pragma unroll 2
    for (int j = 0; j < NC; ++j) {
        const float4 yj = ytile[j];
        const float dot = x0 * yj.x + x1 * yj.y + x2 * yj.z;
        float r2 = fmaf(-2.0f, dot, xsq + yj.w);
        r2 = fmaxf(r2, 0.0f);
        const float f = 0.5f * r2 * __logf(fmaxf(r2, 1e-37f));
        const float* __restrict__ cj = &coeffs[(size_t)j * SOUT];
        #pragma unroll
        for (int s = 0; s < SOUT; ++s) acc[s] = fmaf(f, cj[s], acc[s]);
    }
    float4* o4 = (float4*)&out[(size_t)q * SOUT];
    #pragma unroll
    for (int s = 0; s < SOUT / 4; ++s)
        o4[s] = make_float4(acc[4 * s], acc[4 * s + 1], acc[4 * s + 2], acc[4 * s + 3]);
}

extern "C" void kernel_launch(void* const* d_in, const int* in_sizes, int n_in,
                              void* d_out, int out_size, void* d_ws, size_t ws_size,
                              hipStream_t stream) {
    const float* x      = (const float*)d_in[0];
    const float* y      = (const float*)d_in[1];
    const float* coeffs = (const float*)d_in[2];
    const float* shift  = (const float*)d_in[3];
    const float* scale  = (const float*)d_in[4];
    float* out = (float*)d_out;

    const size_t bp_bytes = (size_t)65 * 4 * 2 * 64 * 8 * sizeof(_Float16); // 532,480
    const size_t ye_bytes = (size_t)KTOT * 8 * sizeof(_Float16);            //  66,560

    if (ws_size >= bp_bytes + ye_bytes) {
        _Float16* bpw = (_Float16*)d_ws;
        _Float16* yep = (_Float16*)((char*)d_ws + bp_bytes);
        hipLaunchKernelGGL(prep_bpack, dim3((65 * 4 * 2 * 64 + 255) / 256), dim3(256),
                           0, stream, coeffs, bpw);
        hipLaunchKernelGGL(prep_ye, dim3((KTOT + 255) / 256), dim3(256),
                           0, stream, y, yep);
        hipLaunchKernelGGL(rbf_mfma14, dim3(NQ / BM), dim3(256), 0, stream,
                           x, yep, shift, scale, bpw, out);
    } else {
        hipLaunchKernelGGL(rbf_tps_fallback, dim3(NQ / 256), dim3(256),
                           0, stream, x, y, coeffs, shift, scale, out);
    }
}